// Round 8
// baseline (375.232 us; speedup 1.0000x reference)
//
#include <hip/hip_runtime.h>
#include <math.h>

// ---------------------------------------------------------------------------
// TransformerEncoderLayer: B=4 S=1024 D=1024 H=16 HD=64 F=4096, fp32 in/out.
// bf16 MFMA GEMMs with DOUBLE-BUFFERED BK=32 staging (loads for k+1 issued
// after the barrier, consumed next iter -> vmcnt drain overlapped with a full
// iter of compute; r7 showed the 2-barrier drain, not HBM, was the limiter)
// + XOR bank swizzle (0 conflicts) + 2D XCD region remap + LDS-transpose
// epilogue + flash attention (no-max softmax, dbuf K/V) + split-K.
// ---------------------------------------------------------------------------

typedef __bf16 bf16;
typedef __bf16 bf16x8 __attribute__((ext_vector_type(8)));
typedef __bf16 bf16x4 __attribute__((ext_vector_type(4)));
typedef float floatx4 __attribute__((ext_vector_type(4)));

#if __has_builtin(__builtin_amdgcn_exp2f)
#define EXP2(x) __builtin_amdgcn_exp2f(x)
#else
#define EXP2(x) exp2f(x)
#endif

#define QSCALE_CONST 0.18033688011112042f  // 0.125 * log2(e)

static __device__ __forceinline__ void async_cp16(const bf16* g, bf16* l) {
  __builtin_amdgcn_global_load_lds(
      (const __attribute__((address_space(1))) void*)g,
      (__attribute__((address_space(3))) void*)l, 16, 0, 0);
}

// 2D/3D XCD region remap (xcd = linear_id % 8 -> contiguous tile region).
template <int SX, int SY, int SZ>
static __device__ __forceinline__ void xcd_remap2(int gx, int gy, int gz,
                                                  int& bx, int& by, int& bz) {
  int l = bx + gx * (by + gy * bz);
  int xcd = l & 7;
  int idx = l >> 3;
  int lx = gx / SX, ly = gy / SY, lz = gz / SZ;
  int rx = xcd % SX, ry = (xcd / SX) % SY, rz = xcd / (SX * SY);
  int ibx = idx % lx;
  int r2 = idx / lx;
  int iby = r2 % ly;
  int ibz = r2 / ly;
  bx = rx * lx + ibx;
  by = ry * ly + iby;
  bz = rz * lz + ibz;
}

// ---------------------------------------------------------------------------
// bf16 GEMM, BK=32 double-buffered swizzled staging, LDS-transpose epilogue.
// C[M,N] = A[M,K] Bt[N,K]^T (+bias)(relu)(QSC cols<1024)(VT: n0>=2048 blocks
// write ONLY Vt [B,H,HD,S] via col-major LDS epilogue).
// Staging rows: 32 bf16 = 4 chunks of 16B; chunk slot = c ^ ((row>>1)&3)
// -> fragment ds_read_b128 lands 2 lanes/bank (free).
// ---------------------------------------------------------------------------
template <int RELU, int QSC, int VT, int SX, int SY>
__global__ __launch_bounds__(256) void gemm_bt(
    const bf16* __restrict__ A, long lda,
    const bf16* __restrict__ Bt, long ldb,
    bf16* __restrict__ C, long ldc,
    const float* __restrict__ bias, int Kd, bf16* __restrict__ Vt)
{
  __shared__ __align__(16) bf16 As[2][128 * 32];
  __shared__ __align__(16) bf16 Bs[2][128 * 32];

  const int t = threadIdx.x;
  const int lane = t & 63, wave = t >> 6;
  const int wr = wave >> 1, wc = wave & 1;
  int bx = blockIdx.x, by = blockIdx.y, bz = 0;
  xcd_remap2<SX, SY, 1>(gridDim.x, gridDim.y, 1, bx, by, bz);
  const long m0 = (long)by * 128;
  const long n0 = (long)bx * 128;

  // staging: rep in {0,1}; slot L = rep*256+t; row=L>>2, cs=L&3,
  // global chunk c = cs ^ ((row>>1)&3)
  const bf16* gA[2];
  const bf16* gB[2];
  int lofs[2];
#pragma unroll
  for (int rep = 0; rep < 2; ++rep) {
    int L = rep * 256 + t;
    int r = L >> 2, cs = L & 3, c = cs ^ ((r >> 1) & 3);
    gA[rep] = A + (m0 + r) * lda + c * 8;
    gB[rep] = Bt + (n0 + r) * ldb + c * 8;
    lofs[rep] = L * 8;
  }

  const int mrow = lane & 15;
  const int quad = lane >> 4;
  int a_off[4], b_off[4];
#pragma unroll
  for (int i = 0; i < 4; ++i) {
    int ra = wr * 64 + i * 16 + mrow;
    a_off[i] = ra * 32 + ((quad ^ ((ra >> 1) & 3)) << 3);
    int rb = wc * 64 + i * 16 + mrow;
    b_off[i] = rb * 32 + ((quad ^ ((rb >> 1) & 3)) << 3);
  }

  floatx4 acc[4][4] = {};

  // prefetch kt=0 into buf 0
#pragma unroll
  for (int rep = 0; rep < 2; ++rep) {
    async_cp16(gA[rep], &As[0][lofs[rep]]);
    async_cp16(gB[rep], &Bs[0][lofs[rep]]);
    gA[rep] += 32; gB[rep] += 32;
  }

  const int ktn = Kd >> 5;
  for (int kt = 0; kt < ktn; ++kt) {
    const int cur = kt & 1;
    __syncthreads();  // buf[cur]'s loads (issued last iter) drained here
    if (kt + 1 < ktn) {
      const int nxt = cur ^ 1;
#pragma unroll
      for (int rep = 0; rep < 2; ++rep) {
        async_cp16(gA[rep], &As[nxt][lofs[rep]]);
        async_cp16(gB[rep], &Bs[nxt][lofs[rep]]);
        gA[rep] += 32; gB[rep] += 32;
      }
    }
    bf16x8 af[4], bfr[4];
#pragma unroll
    for (int i = 0; i < 4; ++i) af[i] = *(const bf16x8*)&As[cur][a_off[i]];
#pragma unroll
    for (int j = 0; j < 4; ++j) bfr[j] = *(const bf16x8*)&Bs[cur][b_off[j]];
#pragma unroll
    for (int i = 0; i < 4; ++i)
#pragma unroll
      for (int j = 0; j < 4; ++j)
        acc[i][j] = __builtin_amdgcn_mfma_f32_16x16x32_bf16(
            af[i], bfr[j], acc[i][j], 0, 0, 0);
  }

  // ---- epilogue via per-wave 64x64 (8 KB) LDS region ----
  __syncthreads();
  bf16* ep = (wave < 2) ? &As[wave][0] : &Bs[wave - 2][0];
  const int rr = lane >> 3, cc2 = lane & 7;

  if (!VT || n0 < 2048) {
#pragma unroll
    for (int i = 0; i < 4; ++i)
#pragma unroll
      for (int j = 0; j < 4; ++j) {
        int col = j * 16 + mrow;
        float bsv = bias[(int)n0 + wc * 64 + col];
#pragma unroll
        for (int r = 0; r < 4; ++r) {
          int row = i * 16 + quad * 4 + r;
          float v = acc[i][j][r] + bsv;
          if (RELU) v = fmaxf(v, 0.f);
          if (QSC && n0 < 1024) v *= QSCALE_CONST;
          int sw = (row ^ (row >> 3)) & 7;
          ep[row * 64 + (((col >> 3) ^ sw) << 3) + (col & 7)] = (bf16)v;
        }
      }
#pragma unroll
    for (int p = 0; p < 8; ++p) {
      int row = p * 8 + rr;
      int sw = (row ^ (row >> 3)) & 7;
      bf16x8 v = *(const bf16x8*)&ep[row * 64 + ((cc2 ^ sw) << 3)];
      *(bf16x8*)&C[(m0 + wr * 64 + row) * ldc + n0 + wc * 64 + cc2 * 8] = v;
    }
  } else {
    // V columns: col-major [c][row]
#pragma unroll
    for (int i = 0; i < 4; ++i)
#pragma unroll
      for (int j = 0; j < 4; ++j) {
        int c = j * 16 + mrow;
        float bsv = bias[(int)n0 + wc * 64 + c];
#pragma unroll
        for (int r = 0; r < 4; ++r) {
          int row = i * 16 + quad * 4 + r;
          float v = acc[i][j][r] + bsv;
          ep[c * 64 + (((row >> 3) ^ (c & 7)) << 3) + (row & 7)] = (bf16)v;
        }
      }
    int hh = ((int)n0 - 2048 + wc * 64) >> 6;
    long bb = m0 >> 10;
    long srow = (m0 & 1023) + wr * 64;
    bf16* Vbase = Vt + ((bb * 16 + hh) * 64) * (long)1024;
#pragma unroll
    for (int p = 0; p < 8; ++p) {
      int c = p * 8 + rr;
      bf16x8 v = *(const bf16x8*)&ep[c * 64 + ((cc2 ^ (c & 7)) << 3)];
      *(bf16x8*)&Vbase[(long)c * 1024 + srow + cc2 * 8] = v;
    }
  }
}

// ---------------------------------------------------------------------------
// Split-K GEMM, BK=32 double-buffered; P[z][M,N] fp32 partials.
// ---------------------------------------------------------------------------
template <int SX, int SY, int SZ>
__global__ __launch_bounds__(256) void gemm_splitk(
    const bf16* __restrict__ A, long lda,
    const bf16* __restrict__ Bt, long ldb,
    float* __restrict__ P, long ldc, long pstride, int Kh)
{
  __shared__ __align__(16) bf16 As[2][128 * 32];
  __shared__ __align__(16) bf16 Bs[2][128 * 32];

  const int t = threadIdx.x;
  const int lane = t & 63, wave = t >> 6;
  const int wr = wave >> 1, wc = wave & 1;
  int bx = blockIdx.x, by = blockIdx.y, bz = blockIdx.z;
  xcd_remap2<SX, SY, SZ>(gridDim.x, gridDim.y, gridDim.z, bx, by, bz);
  const long m0 = (long)by * 128;
  const long n0 = (long)bx * 128;
  const long koff = (long)bz * Kh;

  const bf16* gA[2];
  const bf16* gB[2];
  int lofs[2];
#pragma unroll
  for (int rep = 0; rep < 2; ++rep) {
    int L = rep * 256 + t;
    int r = L >> 2, cs = L & 3, c = cs ^ ((r >> 1) & 3);
    gA[rep] = A + (m0 + r) * lda + koff + c * 8;
    gB[rep] = Bt + (n0 + r) * ldb + koff + c * 8;
    lofs[rep] = L * 8;
  }

  const int mrow = lane & 15;
  const int quad = lane >> 4;
  int a_off[4], b_off[4];
#pragma unroll
  for (int i = 0; i < 4; ++i) {
    int ra = wr * 64 + i * 16 + mrow;
    a_off[i] = ra * 32 + ((quad ^ ((ra >> 1) & 3)) << 3);
    int rb = wc * 64 + i * 16 + mrow;
    b_off[i] = rb * 32 + ((quad ^ ((rb >> 1) & 3)) << 3);
  }

  floatx4 acc[4][4] = {};

#pragma unroll
  for (int rep = 0; rep < 2; ++rep) {
    async_cp16(gA[rep], &As[0][lofs[rep]]);
    async_cp16(gB[rep], &Bs[0][lofs[rep]]);
    gA[rep] += 32; gB[rep] += 32;
  }

  const int ktn = Kh >> 5;
  for (int kt = 0; kt < ktn; ++kt) {
    const int cur = kt & 1;
    __syncthreads();
    if (kt + 1 < ktn) {
      const int nxt = cur ^ 1;
#pragma unroll
      for (int rep = 0; rep < 2; ++rep) {
        async_cp16(gA[rep], &As[nxt][lofs[rep]]);
        async_cp16(gB[rep], &Bs[nxt][lofs[rep]]);
        gA[rep] += 32; gB[rep] += 32;
      }
    }
    bf16x8 af[4], bfr[4];
#pragma unroll
    for (int i = 0; i < 4; ++i) af[i] = *(const bf16x8*)&As[cur][a_off[i]];
#pragma unroll
    for (int j = 0; j < 4; ++j) bfr[j] = *(const bf16x8*)&Bs[cur][b_off[j]];
#pragma unroll
    for (int i = 0; i < 4; ++i)
#pragma unroll
      for (int j = 0; j < 4; ++j)
        acc[i][j] = __builtin_amdgcn_mfma_f32_16x16x32_bf16(
            af[i], bfr[j], acc[i][j], 0, 0, 0);
  }

  float* Pz = P + (long)bz * pstride;
#pragma unroll
  for (int i = 0; i < 4; ++i) {
    long rowb = m0 + wr * 64 + i * 16 + quad * 4;
#pragma unroll
    for (int j = 0; j < 4; ++j) {
      int col = (int)n0 + wc * 64 + j * 16 + mrow;
#pragma unroll
      for (int r = 0; r < 4; ++r)
        Pz[(rowb + r) * ldc + col] = acc[i][j][r];
    }
  }
}

// ---------------------------------------------------------------------------
// Flash attention, no-max softmax, double-buffered K/V staging.
// ---------------------------------------------------------------------------
__global__ __launch_bounds__(256) void flash_attn(
    const bf16* __restrict__ Q, const bf16* __restrict__ K, long ldqk,
    const bf16* __restrict__ Vt, bf16* __restrict__ O)
{
  __shared__ __align__(16) bf16 Qs[128 * 64];
  __shared__ __align__(16) bf16 Ks[2][64 * 64];
  __shared__ __align__(16) bf16 Vs[2][64 * 64];
  __shared__ __align__(16) bf16 Ps[4 * 32 * 64];

  const int t = threadIdx.x;
  const int lane = t & 63, wave = t >> 6;
  const int mrow = lane & 15, quad = lane >> 4;
  int bx = blockIdx.x, by = blockIdx.y, bz = 0;
  xcd_remap2<1, 8, 1>(gridDim.x, gridDim.y, 1, bx, by, bz);
  const int bh = by, b = bh >> 4, h = bh & 15;
  const long q0 = (long)bx * 128;

  const bf16* Qb = Q + (long)b * 1024 * ldqk + h * 64;
  const bf16* Kb = K + (long)b * 1024 * ldqk + h * 64;
  const bf16* Vb = Vt + (long)bh * 64 * 1024;

  // stage Q + prefetch K/V tile 0
#pragma unroll
  for (int rep = 0; rep < 4; ++rep) {
    int L = rep * 256 + t;
    int r = L >> 3, cs = L & 7, c = cs ^ (r & 7);
    async_cp16(Qb + (q0 + r) * ldqk + c * 8, &Qs[L * 8]);
  }
  int kr[2], kc[2], klofs[2];
#pragma unroll
  for (int rep = 0; rep < 2; ++rep) {
    int L = rep * 256 + t;
    kr[rep] = L >> 3;
    int cs = L & 7;
    kc[rep] = cs ^ (kr[rep] & 7);
    klofs[rep] = L * 8;
    async_cp16(Kb + (long)kr[rep] * ldqk + kc[rep] * 8, &Ks[0][klofs[rep]]);
    async_cp16(Vb + (long)kr[rep] * 1024 + kc[rep] * 8, &Vs[0][klofs[rep]]);
  }

  floatx4 oacc[2][4] = {};
  float l_sum[2][4] = {};

  int qs_off[2][2], kv_off[4][2], ps_r[2][2];
#pragma unroll
  for (int kk = 0; kk < 2; ++kk) {
    int cs = ((kk * 4 + quad) ^ (mrow & 7)) * 8;
#pragma unroll
    for (int i = 0; i < 2; ++i) {
      qs_off[i][kk] = (wave * 32 + i * 16 + mrow) * 64 + cs;
      ps_r[i][kk]   = wave * 2048 + (i * 16 + mrow) * 64 + cs;
    }
#pragma unroll
    for (int j = 0; j < 4; ++j)
      kv_off[j][kk] = (j * 16 + mrow) * 64 + cs;
  }

  for (int kt = 0; kt < 16; ++kt) {
    const int cur = kt & 1;
    __syncthreads();
    if (kt + 1 < 16) {
      const int nxt = cur ^ 1;
      const long k0n = (long)(kt + 1) * 64;
#pragma unroll
      for (int rep = 0; rep < 2; ++rep) {
        async_cp16(Kb + (k0n + kr[rep]) * ldqk + kc[rep] * 8,
                   &Ks[nxt][klofs[rep]]);
        async_cp16(Vb + (long)kr[rep] * 1024 + k0n + kc[rep] * 8,
                   &Vs[nxt][klofs[rep]]);
      }
    }

    floatx4 sacc[2][4] = {};
#pragma unroll
    for (int kk = 0; kk < 2; ++kk) {
      bf16x8 aq[2], bk4[4];
#pragma unroll
      for (int i = 0; i < 2; ++i) aq[i] = *(const bf16x8*)&Qs[qs_off[i][kk]];
#pragma unroll
      for (int j = 0; j < 4; ++j)
        bk4[j] = *(const bf16x8*)&Ks[cur][kv_off[j][kk]];
#pragma unroll
      for (int i = 0; i < 2; ++i)
#pragma unroll
        for (int j = 0; j < 4; ++j)
          sacc[i][j] = __builtin_amdgcn_mfma_f32_16x16x32_bf16(
              aq[i], bk4[j], sacc[i][j], 0, 0, 0);
    }

#pragma unroll
    for (int i = 0; i < 2; ++i) {
#pragma unroll
      for (int r = 0; r < 4; ++r) {
        float p0 = EXP2(sacc[i][0][r]);
        float p1 = EXP2(sacc[i][1][r]);
        float p2 = EXP2(sacc[i][2][r]);
        float p3 = EXP2(sacc[i][3][r]);
        l_sum[i][r] += (p0 + p1) + (p2 + p3);
        int row = i * 16 + quad * 4 + r;
        int base = wave * 2048 + row * 64;
        int rs = row & 7;
        Ps[base + (((0 * 16 + mrow) >> 3) ^ rs) * 8 + (mrow & 7)] = (bf16)p0;
        Ps[base + (((1 * 16 + mrow) >> 3) ^ rs) * 8 + (mrow & 7)] = (bf16)p1;
        Ps[base + (((2 * 16 + mrow) >> 3) ^ rs) * 8 + (mrow & 7)] = (bf16)p2;
        Ps[base + (((3 * 16 + mrow) >> 3) ^ rs) * 8 + (mrow & 7)] = (bf16)p3;
      }
    }

#pragma unroll
    for (int kk = 0; kk < 2; ++kk) {
      bf16x8 ap[2], bv4[4];
#pragma unroll
      for (int i = 0; i < 2; ++i) ap[i] = *(const bf16x8*)&Ps[ps_r[i][kk]];
#pragma unroll
      for (int j = 0; j < 4; ++j)
        bv4[j] = *(const bf16x8*)&Vs[cur][kv_off[j][kk]];
#pragma unroll
      for (int i = 0; i < 2; ++i)
#pragma unroll
        for (int j = 0; j < 4; ++j)
          oacc[i][j] = __builtin_amdgcn_mfma_f32_16x16x32_bf16(
              ap[i], bv4[j], oacc[i][j], 0, 0, 0);
    }
  }

  bf16* Op = O + ((long)b * 1024 + q0 + wave * 32) * 1024 + h * 64;
#pragma unroll
  for (int i = 0; i < 2; ++i)
#pragma unroll
    for (int r = 0; r < 4; ++r) {
      float l = l_sum[i][r];
      l += __shfl_xor(l, 1, 64);
      l += __shfl_xor(l, 2, 64);
      l += __shfl_xor(l, 4, 64);
      l += __shfl_xor(l, 8, 64);
      float inv = 1.f / l;
      int row = i * 16 + quad * 4 + r;
#pragma unroll
      for (int j = 0; j < 4; ++j)
        Op[(long)row * 1024 + j * 16 + mrow] = (bf16)(oacc[i][j][r] * inv);
    }
}

// ---------------------------------------------------------------------------
// Merged prep: LN1 (blocks 0..4095) + 6 weight transposes + bias pack.
// ---------------------------------------------------------------------------
__global__ __launch_bounds__(256) void prep_ln(
    const float* __restrict__ x, const float* __restrict__ ln1g,
    const float* __restrict__ ln1b, bf16* __restrict__ XN,
    const float* __restrict__ Wq, const float* __restrict__ Wk,
    const float* __restrict__ Wv, const float* __restrict__ Wo,
    const float* __restrict__ W1, const float* __restrict__ W2,
    const float* __restrict__ bq, const float* __restrict__ bk,
    const float* __restrict__ bv,
    bf16* __restrict__ WqT, bf16* __restrict__ WkT, bf16* __restrict__ WvT,
    bf16* __restrict__ WoT, bf16* __restrict__ W1T, bf16* __restrict__ W2T,
    float* __restrict__ Bc)
{
  __shared__ __align__(16) char smem_raw[64 * 65 * 2];
  const int blk0 = blockIdx.x;
  const int t = threadIdx.x;

  if (blk0 < 4096) {  // --- LN1 row ---
    float* sm = (float*)smem_raw;
    long row = blk0;
    const float* xr = x + row * 1024;
    int lane = t & 63, wv = t >> 6;
    float4 v = *(const float4*)&xr[t * 4];
    float s = v.x + v.y + v.z + v.w;
#pragma unroll
    for (int o = 32; o > 0; o >>= 1) s += __shfl_xor(s, o, 64);
    if (lane == 0) sm[wv] = s;
    __syncthreads();
    float mean = (sm[0] + sm[1] + sm[2] + sm[3]) * (1.f / 1024.f);
    __syncthreads();
    float d0 = v.x - mean, d1 = v.y - mean, d2 = v.z - mean, d3 = v.w - mean;
    float s2 = d0 * d0 + d1 * d1 + d2 * d2 + d3 * d3;
#pragma unroll
    for (int o = 32; o > 0; o >>= 1) s2 += __shfl_xor(s2, o, 64);
    if (lane == 0) sm[wv] = s2;
    __syncthreads();
    float var = (sm[0] + sm[1] + sm[2] + sm[3]) * (1.f / 1024.f);
    float rstd = rsqrtf(var + 1e-6f);
    float4 gg = *(const float4*)&ln1g[t * 4];
    float4 bb = *(const float4*)&ln1b[t * 4];
    bf16x4 o;
    o[0] = (bf16)(d0 * rstd * gg.x + bb.x);
    o[1] = (bf16)(d1 * rstd * gg.y + bb.y);
    o[2] = (bf16)(d2 * rstd * gg.z + bb.z);
    o[3] = (bf16)(d3 * rstd * gg.w + bb.w);
    *(bf16x4*)&XN[row * 1024 + t * 4] = o;
    return;
  }

  const int blk = blk0 - 4096;
  if (blk >= 3072) {  // --- bias pack ---
    int i = (blk - 3072) * 256 + t;
    float v = (i < 1024) ? bq[i] : (i < 2048 ? bk[i - 1024] : bv[i - 2048]);
    Bc[i] = v;
    return;
  }

  // --- weight transpose fp32 [K,N] -> bf16 [N,K] ---
  typedef bf16 tile_t[64][65];
  tile_t& tile = *(tile_t*)smem_raw;
  const float* S;
  bf16* Dst;
  long ldS, ldD;
  int bx, by;
  if (blk < 1024) {
    int j = blk >> 8, rem = blk & 255;
    if (j == 0)      { S = Wq; Dst = WqT; }
    else if (j == 1) { S = Wk; Dst = WkT; }
    else if (j == 2) { S = Wv; Dst = WvT; }
    else             { S = Wo; Dst = WoT; }
    ldS = 1024; ldD = 1024; bx = rem & 15; by = rem >> 4;
  } else if (blk < 2048) {
    int rem = blk - 1024;
    S = W1; Dst = W1T; ldS = 4096; ldD = 1024; bx = rem & 63; by = rem >> 6;
  } else {
    int rem = blk - 2048;
    S = W2; Dst = W2T; ldS = 1024; ldD = 4096; bx = rem & 15; by = rem >> 4;
  }

  long r0 = (long)by * 64, c0 = (long)bx * 64;
#pragma unroll
  for (int rep = 0; rep < 16; ++rep) {
    int idx = rep * 256 + t;
    int r = idx >> 6, c = idx & 63;
    tile[c][r] = (bf16)S[(r0 + r) * ldS + c0 + c];
  }
  __syncthreads();
#pragma unroll
  for (int rep = 0; rep < 16; ++rep) {
    int idx = rep * 256 + t;
    int r = idx >> 6, c = idx & 63;
    Dst[(c0 + r) * ldD + r0 + c] = tile[r][c];
  }
}

// ---------------------------------------------------------------------------
// Wo split-K(2) reduce + residual + LN2 fused.
// ---------------------------------------------------------------------------
__global__ __launch_bounds__(256) void reduce_ln(
    const float* __restrict__ P, long pstride,
    const float* __restrict__ bo, const float* __restrict__ x,
    const float* __restrict__ g, const float* __restrict__ b,
    float* __restrict__ Hr, bf16* __restrict__ HN)
{
  __shared__ float sm[4];
  long row = blockIdx.x;
  int t = threadIdx.x, lane = t & 63, wv = t >> 6;
  long base = row * 1024 + t * 4;
  float4 p0 = *(const float4*)&P[base];
  float4 p1 = *(const float4*)&P[pstride + base];
  float4 xr = *(const float4*)&x[base];
  float4 bb0 = *(const float4*)&bo[t * 4];
  float h0 = p0.x + p1.x + bb0.x + xr.x;
  float h1 = p0.y + p1.y + bb0.y + xr.y;
  float h2 = p0.z + p1.z + bb0.z + xr.z;
  float h3 = p0.w + p1.w + bb0.w + xr.w;
  float4 hv = {h0, h1, h2, h3};
  *(float4*)&Hr[base] = hv;

  float s = h0 + h1 + h2 + h3;
#pragma unroll
  for (int o = 32; o > 0; o >>= 1) s += __shfl_xor(s, o, 64);
  if (lane == 0) sm[wv] = s;
  __syncthreads();
  float mean = (sm[0] + sm[1] + sm[2] + sm[3]) * (1.f / 1024.f);
  __syncthreads();
  float d0 = h0 - mean, d1 = h1 - mean, d2 = h2 - mean, d3 = h3 - mean;
  float s2 = d0 * d0 + d1 * d1 + d2 * d2 + d3 * d3;
#pragma unroll
  for (int o = 32; o > 0; o >>= 1) s2 += __shfl_xor(s2, o, 64);
  if (lane == 0) sm[wv] = s2;
  __syncthreads();
  float var = (sm[0] + sm[1] + sm[2] + sm[3]) * (1.f / 1024.f);
  float rstd = rsqrtf(var + 1e-6f);
  float4 gg = *(const float4*)&g[t * 4];
  float4 bb = *(const float4*)&b[t * 4];
  bf16x4 o;
  o[0] = (bf16)(d0 * rstd * gg.x + bb.x);
  o[1] = (bf16)(d1 * rstd * gg.y + bb.y);
  o[2] = (bf16)(d2 * rstd * gg.z + bb.z);
  o[3] = (bf16)(d3 * rstd * gg.w + bb.w);
  *(bf16x4*)&HN[row * 1024 + t * 4] = o;
}

// ---------------------------------------------------------------------------
// FFN2 split-K(4) reduce: out = p0+p1+p2+p3 + b2 + Hr.
// ---------------------------------------------------------------------------
__global__ __launch_bounds__(256) void reduce_add4(
    const float* __restrict__ P, long pstride,
    const float* __restrict__ b2, const float* __restrict__ Hr,
    float* __restrict__ Out)
{
  long row = blockIdx.x;
  int t = threadIdx.x;
  long base = row * 1024 + t * 4;
  float4 p0 = *(const float4*)&P[base];
  float4 p1 = *(const float4*)&P[pstride + base];
  float4 p2 = *(const float4*)&P[2 * pstride + base];
  float4 p3 = *(const float4*)&P[3 * pstride + base];
  float4 hr = *(const float4*)&Hr[base];
  float4 bb = *(const float4*)&b2[t * 4];
  float4 o;
  o.x = (p0.x + p1.x) + (p2.x + p3.x) + bb.x + hr.x;
  o.y = (p0.y + p1.y) + (p2.y + p3.y) + bb.y + hr.y;
  o.z = (p0.z + p1.z) + (p2.z + p3.z) + bb.z + hr.z;
  o.w = (p0.w + p1.w) + (p2.w + p3.w) + bb.w + hr.w;
  *(float4*)&Out[base] = o;
}

// ---------------------------------------------------------------------------
extern "C" void kernel_launch(void* const* d_in, const int* in_sizes, int n_in,
                              void* d_out, int out_size, void* d_ws,
                              size_t ws_size, hipStream_t stream)
{
  const int D = 1024, F = 4096;
  const long M = 4096;

  const float* x    = (const float*)d_in[0];
  const float* ln1g = (const float*)d_in[3];
  const float* ln1b = (const float*)d_in[4];
  const float* Wq   = (const float*)d_in[5];
  const float* bq   = (const float*)d_in[6];
  const float* Wk   = (const float*)d_in[7];
  const float* bk   = (const float*)d_in[8];
  const float* Wv   = (const float*)d_in[9];
  const float* bv   = (const float*)d_in[10];
  const float* Wo   = (const float*)d_in[11];
  const float* bo   = (const float*)d_in[12];
  const float* ln2g = (const float*)d_in[13];
  const float* ln2b = (const float*)d_in[14];
  const float* W1   = (const float*)d_in[15];
  const float* b1   = (const float*)d_in[16];
  const float* W2   = (const float*)d_in[17];
  const float* b2   = (const float*)d_in[18];

  char* ws = (char*)d_ws;
  auto alloc = [&](size_t bytes) {
    char* p = ws;
    ws += (bytes + 255) & ~(size_t)255;
    return p;
  };
  bf16* WqT = (bf16*)alloc((size_t)D * D * 2);    // must stay contiguous
  bf16* WkT = (bf16*)alloc((size_t)D * D * 2);
  bf16* WvT = (bf16*)alloc((size_t)D * D * 2);
  bf16* WoT = (bf16*)alloc((size_t)D * D * 2);
  bf16* W1T = (bf16*)alloc((size_t)D * F * 2);    // [F, D]
  bf16* W2T = (bf16*)alloc((size_t)F * D * 2);    // [D, F]
  float* Bc = (float*)alloc((size_t)3072 * 4);
  bf16* XN  = (bf16*)alloc((size_t)M * D * 2);
  bf16* QKV = (bf16*)alloc((size_t)M * 3072 * 2);
  bf16* Vt  = (bf16*)alloc((size_t)M * D * 2);
  bf16* CTX = (bf16*)alloc((size_t)M * D * 2);
  float* Pw = (float*)alloc((size_t)2 * M * D * 4);  // Wo splitK partials
  float* Hr = (float*)alloc((size_t)M * D * 4);
  bf16* HN  = (bf16*)alloc((size_t)M * D * 2);
  bf16* T1  = (bf16*)alloc((size_t)M * F * 2);
  float* Pf = (float*)alloc((size_t)4 * M * D * 4);  // FFN2 splitK partials
  float* Of = (float*)d_out;

  dim3 blk(256);

  // merged LN1 + weight prep
  prep_ln<<<dim3(4096 + 3084), blk, 0, stream>>>(
      x, ln1g, ln1b, XN,
      Wq, Wk, Wv, Wo, W1, W2, bq, bk, bv,
      WqT, WkT, WvT, WoT, W1T, W2T, Bc);

  // fused QKV (Q cols scaled; V col-blocks write ONLY Vt, transposed in LDS)
  gemm_bt<0, 1, 1, 2, 4><<<dim3(24, 32), blk, 0, stream>>>(
      XN, D, WqT, D, QKV, 3072, Bc, D, Vt);

  flash_attn<<<dim3(8, 64), blk, 0, stream>>>(QKV, QKV + 1024, 3072, Vt, CTX);

  // Wo projection split-K=2: 512 blocks
  gemm_splitk<1, 4, 2><<<dim3(8, 32, 2), blk, 0, stream>>>(
      CTX, D, WoT, D, Pw, D, M * D, 512);

  reduce_ln<<<dim3(4096), blk, 0, stream>>>(
      Pw, M * D, bo, x, ln2g, ln2b, Hr, HN);

  // FFN1: relu(HN @ W1T^T + b1) -> T1
  gemm_bt<1, 0, 0, 2, 4><<<dim3(32, 32), blk, 0, stream>>>(
      HN, D, W1T, D, T1, F, b1, D, nullptr);

  // FFN2 split-K=4: 1024 blocks
  gemm_splitk<1, 2, 4><<<dim3(8, 32, 4), blk, 0, stream>>>(
      T1, F, W2T, F, Pf, D, M * D, 1024);

  reduce_add4<<<dim3(4096), blk, 0, stream>>>(Pf, M * D, b2, Hr, Of);
}